// Round 10
// baseline (275.527 us; speedup 1.0000x reference)
//
#include <hip/hip_runtime.h>
#include <math.h>
#include <stdint.h>

#define IN_DIM 256
#define OUT_D 64
#define ROUTIT 4
#define LCAP 48       // register-cached edges per node (6 groups of 8)
#define NG 6          // LCAP/8 fully-unrolled z-register groups
#define BSH 6         // bucket shift: 64 nodes per bucket
#define NBMAX 800     // buckets for n=50000 -> 782
#define PEDGES 4096   // partition: edges per block (16 KB LDS stage), 400 blocks
#define LCCAP 3072    // local_csr sorted-stage capacity (bucket avg ~2095, +21 sigma)
#define HISTB 128     // histogram blocks fused ahead of gemm blocks

typedef float v2f __attribute__((ext_vector_type(2)));
__device__ __forceinline__ v2f pk_fma(v2f a, v2f b, v2f c) {
    return __builtin_elementwise_fma(a, b, c);   // -> v_pk_fma_f32
}

// ---- cross-lane helpers ----
__device__ __forceinline__ float dpp_add_xor1(float x) {
    return x + __int_as_float(__builtin_amdgcn_mov_dpp(__float_as_int(x), 0xB1, 0xF, 0xF, true));
}
__device__ __forceinline__ float dpp_add_xor2(float x) {
    return x + __int_as_float(__builtin_amdgcn_mov_dpp(__float_as_int(x), 0x4E, 0xF, 0xF, true));
}
__device__ __forceinline__ float dpp_add_xor8(float x) {
    return x + __int_as_float(__builtin_amdgcn_mov_dpp(__float_as_int(x), 0x128, 0xF, 0xF, true));
}
__device__ __forceinline__ float swz_add_xor4(float x) {
    return x + __int_as_float(__builtin_amdgcn_ds_swizzle(__float_as_int(x), 0x101F));
}
__device__ __forceinline__ float swz_add_xor16(float x) {
    return x + __int_as_float(__builtin_amdgcn_ds_swizzle(__float_as_int(x), 0x401F));
}

__device__ __forceinline__ void load8p(v2f z[4], const float* p) {
    float4 a = *(const float4*)p;
    float4 b = *(const float4*)(p + 4);
    z[0] = (v2f){a.x, a.y}; z[1] = (v2f){a.z, a.w};
    z[2] = (v2f){b.x, b.y}; z[3] = (v2f){b.z, b.w};
}

// ---------------- fused: [blocks 0..HISTB-1] edge bucket histogram
//                  [blocks HISTB..]           h = l2norm^2(leaky(x@W+b))
// Independent inputs (trg vs x/w/bias); hist rides on CUs gemm leaves idle.
__global__ __launch_bounds__(512, 2) void gemm_hist_kernel(
    const float* __restrict__ x, const float* __restrict__ w,
    const float* __restrict__ bias, float* __restrict__ h, int n,
    const int* __restrict__ trg, int m4, int* __restrict__ bpad, int nb)
{
    __shared__ float wlds[IN_DIM * OUT_D];   // 64 KB (hist blocks alias it as int*)

    if (blockIdx.x < HISTB) {
        int* hist = (int*)wlds;
        for (int i = threadIdx.x; i < nb; i += 512) hist[i] = 0;
        __syncthreads();
        for (int i = blockIdx.x * 512 + threadIdx.x; i < m4; i += 512 * HISTB) {
            int4 t = ((const int4*)trg)[i];
            atomicAdd(&hist[t.x >> BSH], 1);
            atomicAdd(&hist[t.y >> BSH], 1);
            atomicAdd(&hist[t.z >> BSH], 1);
            atomicAdd(&hist[t.w >> BSH], 1);
        }
        __syncthreads();
        for (int i = threadIdx.x; i < nb; i += 512) {
            int c = hist[i];
            if (c) atomicAdd(&bpad[i << 4], c);   // padded: 1 counter per line
        }
        return;
    }

    {
        const float4* wsrc = (const float4*)w;
        float4* wdst = (float4*)wlds;
        #pragma unroll
        for (int i = 0; i < (IN_DIM * OUT_D / 4); i += 512)
            wdst[i + threadIdx.x] = wsrc[i + threadIdx.x];
    }
    __syncthreads();

    int lane = threadIdx.x & 63;
    int wv   = threadIdx.x >> 6;          // 0..7
    int c0   = wv * 8;                    // this wave's capsule
    int base = (blockIdx.x - HISTB) * 256;

    const float* xr[4];
    int rows[4];
    #pragma unroll
    for (int r = 0; r < 4; ++r) {
        rows[r] = base + r * 64 + lane;
        int rc = rows[r] < n ? rows[r] : n - 1;
        xr[r] = x + (size_t)rc * IN_DIM;
    }

    v2f b2[4];
    #pragma unroll
    for (int j = 0; j < 4; ++j) b2[j] = (v2f){bias[c0 + 2*j], bias[c0 + 2*j + 1]};
    v2f acc[4][4];
    #pragma unroll
    for (int r = 0; r < 4; ++r)
        #pragma unroll
        for (int j = 0; j < 4; ++j) acc[r][j] = b2[j];

    float4 xa[4], xb[4];
    #pragma unroll
    for (int r = 0; r < 4; ++r) {
        xa[r] = *(const float4*)(xr[r]);
        xb[r] = *(const float4*)(xr[r] + 4);
    }

    for (int k0 = 0; k0 < IN_DIM; k0 += 8) {
        int kn = (k0 + 8 < IN_DIM) ? k0 + 8 : 0;       // wrap: harmless re-read
        float4 na[4], nb4[4];
        #pragma unroll
        for (int r = 0; r < 4; ++r) {
            na[r]  = *(const float4*)(xr[r] + kn);
            nb4[r] = *(const float4*)(xr[r] + kn + 4);
        }
        const float* wk = wlds + k0 * OUT_D + c0;
        #pragma unroll
        for (int kk = 0; kk < 8; ++kk) {
            float4 w0 = *(const float4*)(wk + kk * OUT_D);      // broadcast b128
            float4 w1 = *(const float4*)(wk + kk * OUT_D + 4);
            v2f wvp[4] = {{w0.x,w0.y},{w0.z,w0.w},{w1.x,w1.y},{w1.z,w1.w}};
            #pragma unroll
            for (int r = 0; r < 4; ++r) {
                float xs = (kk < 4)
                    ? ((kk == 0) ? xa[r].x : (kk == 1) ? xa[r].y : (kk == 2) ? xa[r].z : xa[r].w)
                    : ((kk == 4) ? xb[r].x : (kk == 5) ? xb[r].y : (kk == 6) ? xb[r].z : xb[r].w);
                v2f xs2 = (v2f){xs, xs};
                acc[r][0] = pk_fma(xs2, wvp[0], acc[r][0]);
                acc[r][1] = pk_fma(xs2, wvp[1], acc[r][1]);
                acc[r][2] = pk_fma(xs2, wvp[2], acc[r][2]);
                acc[r][3] = pk_fma(xs2, wvp[3], acc[r][3]);
            }
        }
        #pragma unroll
        for (int r = 0; r < 4; ++r) { xa[r] = na[r]; xb[r] = nb4[r]; }
    }

    #pragma unroll
    for (int r = 0; r < 4; ++r) {
        if (rows[r] < n) {
            float a[8];
            #pragma unroll
            for (int j = 0; j < 4; ++j) { a[2*j] = acc[r][j][0]; a[2*j+1] = acc[r][j][1]; }
            #pragma unroll
            for (int c = 0; c < 8; ++c) a[c] = a[c] > 0.0f ? a[c] : 0.01f * a[c];  // leaky
            #pragma unroll
            for (int rep = 0; rep < 2; ++rep) {           // reference normalizes twice
                float ss = 0.0f;
                #pragma unroll
                for (int d = 0; d < 8; ++d) ss = fmaf(a[d], a[d], ss);
                float inv = 1.0f / fmaxf(sqrtf(ss), 1e-12f);
                #pragma unroll
                for (int d = 0; d < 8; ++d) a[d] *= inv;
            }
            float* hr = h + (size_t)rows[r] * OUT_D + c0;
            float4 o1, o2;
            o1.x=a[0]; o1.y=a[1]; o1.z=a[2]; o1.w=a[3];
            o2.x=a[4]; o2.y=a[5]; o2.z=a[6]; o2.w=a[7];
            *(float4*)hr = o1;
            *(float4*)(hr + 4) = o2;
        }
    }
}

// ---------------- bucket scan (782 buckets; counters live padded in bpad) ----
__global__ __launch_bounds__(64) void bucket_scan_kernel(
    int* __restrict__ bpad, int* __restrict__ bucket_base,
    int nb, int n, int m, int* __restrict__ row_start)
{
    int lane = threadIdx.x;
    int carry = 0;
    for (int base = 0; base < nb; base += 64) {
        int i = base + lane;
        int v = (i < nb) ? bpad[i << 4] : 0;
        int s = v;
        #pragma unroll
        for (int off = 1; off < 64; off <<= 1) {
            int t = __shfl_up(s, off, 64);
            if (lane >= off) s += t;
        }
        if (i < nb) {
            int exc = carry + s - v;
            bucket_base[i] = exc;
            bpad[i << 4]   = exc;     // becomes the claim cursor
        }
        carry += __shfl(s, 63, 64);
    }
    if (lane == 0) { bucket_base[nb] = m; row_start[n] = m; }
}

// ---------------- partition: 4096 edges/block, 400 blocks, ordered copy-out ----
// record = (trg << 16) | src  (both < 65536); bucket = rec >> 22
__global__ __launch_bounds__(1024) void partition_kernel(
    const int* __restrict__ trg, const int* __restrict__ src, int m4,
    uint32_t* __restrict__ epack, int* __restrict__ bpad, int nb)
{
    __shared__ uint32_t stage[PEDGES];   // 16 KB
    __shared__ int hist[NBMAX];
    __shared__ int lbase[NBMAX];
    __shared__ int gdelta[NBMAX];
    for (int i = threadIdx.x; i < nb; i += 1024) hist[i] = 0;
    __syncthreads();
    int i4 = blockIdx.x * (PEDGES / 4) + threadIdx.x;
    int4 t = make_int4(-1,-1,-1,-1), s = make_int4(0,0,0,0);
    bool valid = i4 < m4;
    if (valid) {
        t = ((const int4*)trg)[i4];
        s = ((const int4*)src)[i4];
        atomicAdd(&hist[t.x >> BSH], 1);
        atomicAdd(&hist[t.y >> BSH], 1);
        atomicAdd(&hist[t.z >> BSH], 1);
        atomicAdd(&hist[t.w >> BSH], 1);
    }
    __syncthreads();
    // block-local exclusive scan of hist -> lbase (wave 0)
    if (threadIdx.x < 64) {
        int lane = threadIdx.x;
        int carry = 0;
        for (int b0 = 0; b0 < nb; b0 += 64) {
            int i = b0 + lane;
            int v = (i < nb) ? hist[i] : 0;
            int sc = v;
            #pragma unroll
            for (int off = 1; off < 64; off <<= 1) {
                int u = __shfl_up(sc, off, 64);
                if (lane >= off) sc += u;
            }
            if (i < nb) lbase[i] = carry + sc - v;
            carry += __shfl(sc, 63, 64);
        }
    }
    __syncthreads();
    // claim global runs (padded cursors: one per cache line)
    for (int i = threadIdx.x; i < nb; i += 1024) {
        int c = hist[i];
        int g = c ? atomicAdd(&bpad[i << 4], c) : 0;
        gdelta[i] = g - lbase[i];
    }
    __syncthreads();
    for (int i = threadIdx.x; i < nb; i += 1024) hist[i] = 0;   // reuse as cursor
    __syncthreads();
    if (valid) {
        int tt[4] = {t.x, t.y, t.z, t.w};
        int ss[4] = {s.x, s.y, s.z, s.w};
        #pragma unroll
        for (int q = 0; q < 4; ++q) {
            int b = tt[q] >> BSH;
            int r = atomicAdd(&hist[b], 1);
            stage[lbase[b] + r] = ((uint32_t)tt[q] << 16) | (uint32_t)ss[q];
        }
    }
    __syncthreads();
    // ordered copy-out: consecutive i within a bucket -> consecutive addrs
    int rem = (m4 - blockIdx.x * (PEDGES / 4)) * 4;
    int cnt = rem < PEDGES ? rem : PEDGES;
    for (int i = threadIdx.x; i < cnt; i += 1024) {
        uint32_t p = stage[i];
        int b = (int)(p >> (16 + BSH));
        epack[gdelta[b] + i] = p;
    }
}

// ---------------- local_csr: 64-node buckets, 782 blocks ----------------
__global__ __launch_bounds__(512) void local_csr_kernel(
    const uint32_t* __restrict__ epack, const int* __restrict__ bucket_base,
    int* __restrict__ row_start, int* __restrict__ edge_src, int n)
{
    __shared__ int sorted[LCCAP];   // 12 KB
    __shared__ int hist[64];
    __shared__ int excl[65];
    __shared__ int cursor[64];
    int b = blockIdx.x;
    int ebeg = bucket_base[b], eend = bucket_base[b + 1];
    int cnt = eend - ebeg;
    int node0 = b << BSH;
    if (threadIdx.x < 64) hist[threadIdx.x] = 0;
    __syncthreads();
    for (int e = threadIdx.x; e < cnt; e += 512)
        atomicAdd(&hist[(epack[ebeg + e] >> 16) & 63], 1);
    __syncthreads();
    if (threadIdx.x < 64) {                       // single-wave scan of 64
        int lane = threadIdx.x;
        int v = hist[lane];
        int s = v;
        #pragma unroll
        for (int off = 1; off < 64; off <<= 1) {
            int u = __shfl_up(s, off, 64);
            if (lane >= off) s += u;
        }
        excl[lane] = s - v;
        if (lane == 63) excl[64] = s;
    }
    __syncthreads();
    int nh = n - node0; if (nh > 64) nh = 64;
    for (int i = threadIdx.x; i <= nh; i += 512)
        row_start[node0 + i] = ebeg + excl[i];
    if (threadIdx.x < 64) cursor[threadIdx.x] = excl[threadIdx.x];
    __syncthreads();
    for (int e = threadIdx.x; e < cnt; e += 512) {
        uint32_t p = epack[ebeg + e];
        int r = atomicAdd(&cursor[(p >> 16) & 63], 1);
        int sv = (int)(p & 0xFFFFu);
        if (r < LCCAP) sorted[r] = sv;            // LDS scatter (cheap)
        else edge_src[ebeg + r] = sv;             // safety overflow
    }
    __syncthreads();
    int lim = cnt < LCCAP ? cnt : LCCAP;
    for (int i = threadIdx.x; i < lim; i += 512)
        edge_src[ebeg + i] = sorted[i];           // dense coalesced write
}

// ---------------- routing: wave per node, z in registers, LDS-free (UNCHANGED) --
__device__ __forceinline__ void route_group(const v2f z[4], const v2f c[4], v2f acc[4]) {
    v2f p2 = z[0] * c[0];
    p2 = pk_fma(z[1], c[1], p2);
    p2 = pk_fma(z[2], c[2], p2);
    p2 = pk_fma(z[3], c[3], p2);
    float p = p2[0] + p2[1];
    float ex = __expf(p);               // TAU = 1; |p|<=1 -> no max-subtract
    float sm = dpp_add_xor1(ex);
    sm = dpp_add_xor2(sm);
    sm = dpp_add_xor8(sm);
    float wgt = __fdividef(ex, sm);
    v2f w2 = (v2f){wgt, wgt};
    acc[0] = pk_fma(w2, z[0], acc[0]);
    acc[1] = pk_fma(w2, z[1], acc[1]);
    acc[2] = pk_fma(w2, z[2], acc[2]);
    acc[3] = pk_fma(w2, z[3], acc[3]);
}

__global__ __launch_bounds__(256, 4) void route_kernel(
    const float* __restrict__ h, const int* __restrict__ row_start,
    const int* __restrict__ edge_src, float* __restrict__ out, int n)
{
    int lane = threadIdx.x & 63;
    int wid  = threadIdx.x >> 6;
    int v = blockIdx.x * 4 + wid;
    if (v >= n) return;
    int beg = row_start[v];
    int deg = row_start[v + 1] - beg;
    int nl  = deg < LCAP ? deg : LCAP;
    int ngroups = (nl + 7) >> 3;

    int k  = (lane & 3) | ((lane >> 1) & 4);         // capsule: lane bits 0,1,3
    int eo = ((lane >> 2) & 1) | ((lane >> 3) & 6);  // edge-octet: lane bits 2,4,5

    v2f c[4];
    load8p(c, h + (size_t)v * OUT_D + k * 8);

    v2f z[NG][4];
    #pragma unroll
    for (int g = 0; g < NG; ++g) {
        int e = g * 8 + eo;
        if (e < nl) {
            int s = edge_src[beg + e];
            load8p(z[g], h + (size_t)s * OUT_D + k * 8);
        } else {
            #pragma unroll
            for (int d = 0; d < 4; ++d) z[g][d] = (v2f){0.0f, 0.0f};
        }
    }

    #pragma unroll
    for (int it = 0; it < ROUTIT; ++it) {
        v2f acc[4] = {{0,0},{0,0},{0,0},{0,0}};
        #pragma unroll
        for (int g = 0; g < NG; ++g)
            if (g < ngroups) route_group(z[g], c, acc);   // wave-uniform guard
        if (deg > LCAP) {
            for (int e0 = LCAP; e0 < deg; e0 += 8) {
                int e = e0 + eo;
                v2f zt[4] = {{0,0},{0,0},{0,0},{0,0}};
                if (e < deg) {
                    int s = edge_src[beg + e];
                    load8p(zt, h + (size_t)s * OUT_D + k * 8);
                }
                route_group(zt, c, acc);
            }
        }
        float ss = 0.0f;
        #pragma unroll
        for (int d = 0; d < 8; ++d) {
            float a = acc[d >> 1][d & 1];
            a = swz_add_xor4(a);
            a = swz_add_xor16(a);
            a += __shfl_xor(a, 32, 64);
            float cv = c[d >> 1][d & 1] + a;
            c[d >> 1][d & 1] = cv;
            ss = fmaf(cv, cv, ss);
        }
        float inv = 1.0f / fmaxf(sqrtf(ss), 1e-12f);
        v2f inv2 = (v2f){inv, inv};
        #pragma unroll
        for (int j = 0; j < 4; ++j) c[j] *= inv2;
    }
    if (eo == 0) {                                   // lanes {0-3, 8-11} hold k=0..7
        float* op = out + (size_t)v * OUT_D + k * 8;
        float4 o1, o2;
        o1.x=c[0][0]; o1.y=c[0][1]; o1.z=c[1][0]; o1.w=c[1][1];
        o2.x=c[2][0]; o2.y=c[2][1]; o2.z=c[3][0]; o2.w=c[3][1];
        *(float4*)op = o1;
        *(float4*)(op + 4) = o2;
    }
}

// ---------------- launch ----------------
extern "C" void kernel_launch(void* const* d_in, const int* in_sizes, int n_in,
                              void* d_out, int out_size, void* d_ws, size_t ws_size,
                              hipStream_t stream)
{
    const float* x       = (const float*)d_in[0];
    const int*   src_trg = (const int*)d_in[1];
    const float* w       = (const float*)d_in[2];
    const float* bias    = (const float*)d_in[3];
    float*       out     = (float*)d_out;

    int n = in_sizes[0] / IN_DIM;   // 50000
    int m = in_sizes[1] / 2;        // 1638400
    int m4 = m >> 2;
    int nb = (n + 63) >> BSH;       // 782 buckets
    const int* trg = src_trg;       // row 0 = trg
    const int* src = src_trg + m;   // row 1 = src

    char* wsb = (char*)d_ws;
    size_t off = 0;
    float*    h        = (float*)(wsb + off);    off += (size_t)n * OUT_D * sizeof(float);
    int*      rowstart = (int*)(wsb + off);      off += (size_t)(n + 1) * sizeof(int);
    off = (off + 255) & ~(size_t)255;
    int*      edgesrc  = (int*)(wsb + off);      off += (size_t)m * sizeof(int);
    off = (off + 255) & ~(size_t)255;
    uint32_t* epack    = (uint32_t*)(wsb + off); off += (size_t)m * sizeof(uint32_t);
    int*      bbase    = (int*)(wsb + off);      off += (size_t)(nb + 1) * sizeof(int);
    off = (off + 255) & ~(size_t)255;
    int*      bpad     = (int*)(wsb + off);      off += (size_t)nb * 16 * sizeof(int);

    int gemmb = (n + 255) / 256;    // 196
    hipMemsetAsync(bpad, 0, (size_t)nb * 16 * sizeof(int), stream);
    gemm_hist_kernel<<<HISTB + gemmb, 512, 0, stream>>>(x, w, bias, h, n, trg, m4, bpad, nb);
    bucket_scan_kernel<<<1, 64, 0, stream>>>(bpad, bbase, nb, n, m, rowstart);
    partition_kernel<<<(m + PEDGES - 1) / PEDGES, 1024, 0, stream>>>(trg, src, m4, epack, bpad, nb);
    local_csr_kernel<<<nb, 512, 0, stream>>>(epack, bbase, rowstart, edgesrc, n);
    route_kernel<<<(n + 3) / 4, 256, 0, stream>>>(h, rowstart, edgesrc, out, n);
}